// Round 10
// baseline (373.507 us; speedup 1.0000x reference)
//
#include <hip/hip_runtime.h>

#define NN 100000
#define NE 1600000
#define CH 128

#define PART 512               // nodes per partition
#define NP 196                 // ceil(NN/PART)
#define PCAP 8704              // pair capacity per partition (lambda~8163, +6 sd)
#define NB 391                 // bin blocks: ceil(NE/4/1024)
#define SCAP 64                // LDS slot cap per (block, partition); lambda~21
#define SLAB 1536              // agg: LDS slab cap (64 nodes, lambda~1024, +16 sd)

typedef __attribute__((ext_vector_type(8))) short bf16x8;
typedef __attribute__((ext_vector_type(4))) float f32x4;
typedef unsigned int uint;
typedef unsigned short ushort;

__device__ __forceinline__ ushort f2b(float f) {
    uint u = __builtin_bit_cast(uint, f);
    uint r = (u + 0x7fff + ((u >> 16) & 1)) >> 16;
    return (ushort)r;
}
__device__ __forceinline__ float blo(uint v) { return __builtin_bit_cast(float, v << 16); }
__device__ __forceinline__ float bhi(uint v) { return __builtin_bit_cast(float, v & 0xffff0000u); }

__device__ __forceinline__ void acc8(float* a, uint4 v) {
    a[0] += blo(v.x); a[1] += bhi(v.x);
    a[2] += blo(v.y); a[3] += bhi(v.y);
    a[4] += blo(v.z); a[5] += bhi(v.z);
    a[6] += blo(v.w); a[7] += bhi(v.w);
}

// ---------------- pass 1: LDS-binned edge partitioning ----------------
// pair = (dst_local << 17) | src ; partition p = dst >> 9. int4 edge reads.

__global__ __launch_bounds__(1024) void k_bin(const int4* __restrict__ src4, const int4* __restrict__ dst4,
                                              uint* __restrict__ pcnt, uint* __restrict__ pairbuf) {
    __shared__ uint slots[NP * SCAP];  // 50.2 KB
    __shared__ uint lcnt[NP];
    __shared__ uint lbase[NP];
    int tid = threadIdx.x;
    if (tid < NP) lcnt[tid] = 0;
    __syncthreads();
    int e4 = blockIdx.x * 1024 + tid;
    if (e4 < NE / 4) {
        int4 d4 = dst4[e4];
        int4 s4 = src4[e4];
        int dd[4] = {d4.x, d4.y, d4.z, d4.w};
        int ss[4] = {s4.x, s4.y, s4.z, s4.w};
        #pragma unroll
        for (int j = 0; j < 4; ++j) {
            int p = dd[j] >> 9;
            uint pair = ((uint)(dd[j] & 511) << 17) | (uint)ss[j];
            uint pos = atomicAdd(&lcnt[p], 1u);
            if (pos < SCAP) slots[p * SCAP + pos] = pair;
        }
    }
    __syncthreads();
    if (tid < NP) {
        uint c = lcnt[tid];
        c = c < SCAP ? c : SCAP;
        lcnt[tid] = c;
        lbase[tid] = atomicAdd(&pcnt[tid], c);
    }
    __syncthreads();
    for (int t = tid; t < NP * SCAP; t += 1024) {
        int p = t >> 6;
        uint s = (uint)(t & (SCAP - 1));
        if (s < lcnt[p]) {
            uint idx = lbase[p] + s;
            if (idx < PCAP) pairbuf[(size_t)p * PCAP + idx] = slots[t];
        }
    }
}

// ---------------- pass 2 (fused): CSR build + x cast + W cast ----------------
// blocks [0, NP): per-partition CSR build (latency-bound: <1 block/CU alone).
// blocks [NP, NP+784): x [NN][128] fp32 -> plane-sliced bf16 xb[p][n][32].
// blocks [NP+784, NP+912): k-major B for both layers.

__global__ __launch_bounds__(512) void k_mid(const uint* __restrict__ pcnt, const uint* __restrict__ pairbuf,
                                             int* __restrict__ nbrG, uint* __restrict__ pack,
                                             const float* __restrict__ x, ushort* __restrict__ xb,
                                             const float* __restrict__ Wl1, const float* __restrict__ Wr1,
                                             const float* __restrict__ Wl2, const float* __restrict__ Wr2,
                                             ushort* __restrict__ BtK1, ushort* __restrict__ BtK2) {
    __shared__ uint pairs[PCAP];   // 34.8 KB
    __shared__ uint cnt[PART];
    __shared__ uint rowptr[PART + 1];
    __shared__ uint wpart[8];
    int tid = threadIdx.x;
    int b = blockIdx.x;
    if (b >= NP) {
        int i = b - NP;
        if (i < 784) {               // x cast: plane p = i/196, 196 blocks/plane
            int p = i / 196;
            int n = (i % 196) * 512 + tid;
            if (n >= NN) return;
            const float4* sp = (const float4*)(x + (size_t)n * 128 + p * 32);
            uint4 o[4];
            ushort* op = (ushort*)o;
            #pragma unroll
            for (int q = 0; q < 8; ++q) {
                float4 v = sp[q];
                op[q * 4 + 0] = f2b(v.x);
                op[q * 4 + 1] = f2b(v.y);
                op[q * 4 + 2] = f2b(v.z);
                op[q * 4 + 3] = f2b(v.w);
            }
            uint4* dp = (uint4*)(xb + ((size_t)p * NN + n) * 32);
            #pragma unroll
            for (int q = 0; q < 4; ++q) dp[q] = o[q];
        } else {                     // W cast: BtK[kt][n][c], 128 blocks over 2*32768
            int idx = (i - 784) * 512 + tid;
            int L = idx >> 15;
            int ii = idx & 32767;
            const float* Wl = L ? Wl2 : Wl1;
            const float* Wr = L ? Wr2 : Wr1;
            ushort* BtK = L ? BtK2 : BtK1;
            int c = ii & 31;
            int n = (ii >> 5) & 127;
            int kt = ii >> 12;
            int k = kt * 32 + c;
            float v = (k < 128) ? Wl[k * 128 + n] : Wr[(k - 128) * 128 + n];
            BtK[ii] = f2b(v);
        }
        return;
    }
    // ---- CSR build for partition b ----
    int p = b;
    uint tot = pcnt[p];
    tot = tot < PCAP ? tot : PCAP;
    for (uint i = tid; i < tot; i += 512) pairs[i] = pairbuf[(size_t)p * PCAP + i];
    cnt[tid] = 0;
    __syncthreads();
    for (uint i = tid; i < tot; i += 512) atomicAdd(&cnt[pairs[i] >> 17], 1u);
    __syncthreads();
    uint deg = cnt[tid];
    uint s = deg;
    #pragma unroll
    for (int off = 1; off < 64; off <<= 1) {
        uint t = __shfl_up(s, off, 64);
        if ((tid & 63) >= off) s += t;
    }
    if ((tid & 63) == 63) wpart[tid >> 6] = s;
    __syncthreads();
    uint base = 0;
    int w = tid >> 6;
    #pragma unroll
    for (int q = 0; q < 7; ++q) base += (q < w) ? wpart[q] : 0;
    rowptr[tid] = base + s - deg;
    if (tid == 511) rowptr[512] = base + s;
    cnt[tid] = 0;  // reuse as fill counters
    __syncthreads();
    for (uint i = tid; i < tot; i += 512) {
        uint u = pairs[i];
        uint dl = u >> 17;
        uint pos = rowptr[dl] + atomicAdd(&cnt[dl], 1u);
        nbrG[(size_t)p * PCAP + pos] = (int)(u & 0x1FFFFu);
    }
    {
        int n = p * PART + tid;
        if (n < NN) {
            uint d = rowptr[tid + 1] - rowptr[tid];
            pack[n] = ((uint)(p * PCAP) + rowptr[tid]) | (d << 21);
        }
    }
}

// ---------------- mean aggregation: LDS-staged neighbor slab ----------------
// grid (4, YCHUNK); y0 = chunk offset. Split into 4 launches per layer THIS ROUND
// as a measurement probe: pushes agg dispatches (~15us) below bin/mid/gemm in the
// top-5 table so their true durations become visible. Body identical to R9.

__global__ __launch_bounds__(256) void k_agg(const uint4* __restrict__ feat, const int* __restrict__ nbrG,
                                             const uint* __restrict__ pack, uint4* __restrict__ outb,
                                             int y0) {
    __shared__ int sl[SLAB];
    __shared__ int sh_s0, sh_cnt;
    int plane = blockIdx.x;
    int nb = (blockIdx.y + y0) * 64;  // block node range stays within one 512-partition
    int tid = threadIdx.x;
    int n = nb + (tid >> 2);
    int h = tid & 3;
    if (tid == 0) {
        uint u0 = pack[nb];
        int last = nb + 63 < NN ? nb + 63 : NN - 1;
        uint u1 = pack[last];
        int s0 = (int)(u0 & 0x1FFFFFu);
        sh_s0 = s0;
        sh_cnt = (int)(u1 & 0x1FFFFFu) + (int)(u1 >> 21) - s0;
    }
    __syncthreads();
    int s0 = sh_s0, scnt = sh_cnt;
    bool staged = scnt <= SLAB;
    if (staged) {
        for (int i = tid; i < scnt; i += 256) sl[i] = nbrG[s0 + i];
    }
    __syncthreads();
    if (n >= NN) return;
    uint u = pack[n];
    int s = (int)(u & 0x1FFFFFu);
    int d = (int)(u >> 21);
    const char* fb = (const char*)feat + ((size_t)plane * NN) * 64;
    uint hoff = (uint)h * 16;
    float a[8] = {};
    if (staged) {
        const int* bp = sl + (s - s0);
        int i = 0;
        for (; i + 8 <= d; i += 8) {  // 8 x 64B line requests in flight
            uint off[8];
            uint4 v[8];
            #pragma unroll
            for (int j = 0; j < 8; ++j) off[j] = ((uint)bp[i + j] << 6) | hoff;
            #pragma unroll
            for (int j = 0; j < 8; ++j) v[j] = *(const uint4*)(fb + off[j]);
            #pragma unroll
            for (int j = 0; j < 8; ++j) acc8(a, v[j]);
        }
        for (; i < d; ++i) acc8(a, *(const uint4*)(fb + (((uint)bp[i] << 6) | hoff)));
    } else {  // overflow fallback (P ~ 0): global index reads
        const int* bp = nbrG + s;
        int i = 0;
        for (; i + 4 <= d; i += 4) {
            uint o0 = ((uint)bp[i] << 6) | hoff;
            uint o1 = ((uint)bp[i + 1] << 6) | hoff;
            uint o2 = ((uint)bp[i + 2] << 6) | hoff;
            uint o3 = ((uint)bp[i + 3] << 6) | hoff;
            uint4 v0 = *(const uint4*)(fb + o0);
            uint4 v1 = *(const uint4*)(fb + o1);
            uint4 v2 = *(const uint4*)(fb + o2);
            uint4 v3 = *(const uint4*)(fb + o3);
            acc8(a, v0);
            acc8(a, v1);
            acc8(a, v2);
            acc8(a, v3);
        }
        for (; i < d; ++i) acc8(a, *(const uint4*)(fb + (((uint)bp[i] << 6) | hoff)));
    }
    float id = 1.0f / fmaxf((float)d, 1.0f);
    uint4 r;
    r.x = (uint)f2b(a[0] * id) | ((uint)f2b(a[1] * id) << 16);
    r.y = (uint)f2b(a[2] * id) | ((uint)f2b(a[3] * id) << 16);
    r.z = (uint)f2b(a[4] * id) | ((uint)f2b(a[5] * id) << 16);
    r.w = (uint)f2b(a[6] * id) | ((uint)f2b(a[7] * id) << 16);
    outb[((size_t)plane * NN + n) * 4 + h] = r;
}

// ---------------- MFMA GEMM: out = relu([Am | Ax] @ B + bias) ----------------
// A plane-sliced [4][N][32] bf16; B k-major [8][128][32]. BM=128/block, 32 rows/wave.

template <bool WB16>
__global__ __launch_bounds__(256) void k_gemm(const ushort* __restrict__ Am, const ushort* Ax,
                                              const ushort* __restrict__ BtK, const float* __restrict__ bias,
                                              void* outp, int M) {
    int lane = threadIdx.x & 63;
    int wave = threadIdx.x >> 6;
    int bm = blockIdx.x * 128 + wave * 32;
    int l16 = lane & 15;
    int lk8 = (lane >> 4) * 8;

    f32x4 acc[2][8] = {};
    #pragma unroll
    for (int kt = 0; kt < 8; ++kt) {
        const ushort* A = (kt < 4) ? Am : Ax;
        int p = kt & 3;                          // 32-ch plane index
        bf16x8 af[2];
        #pragma unroll
        for (int mt = 0; mt < 2; ++mt) {
            int row = bm + mt * 16 + l16;
            row = row < M ? row : M - 1;
            af[mt] = *(const bf16x8*)(A + ((size_t)p * NN + row) * 32 + lk8);
        }
        const ushort* Bk = BtK + (size_t)kt * 128 * 32;  // contiguous 8 KB slice, L1-hot
        #pragma unroll
        for (int nt = 0; nt < 8; ++nt) {
            bf16x8 bfr = *(const bf16x8*)(Bk + (size_t)(nt * 16 + l16) * 32 + lk8);
            acc[0][nt] = __builtin_amdgcn_mfma_f32_16x16x32_bf16(af[0], bfr, acc[0][nt], 0, 0, 0);
            acc[1][nt] = __builtin_amdgcn_mfma_f32_16x16x32_bf16(af[1], bfr, acc[1][nt], 0, 0, 0);
        }
    }
    // C/D layout: col = lane&15, row = (lane>>4)*4 + reg
    int mr0 = (lane >> 4) * 4;
    #pragma unroll
    for (int mt = 0; mt < 2; ++mt) {
        #pragma unroll
        for (int r = 0; r < 4; ++r) {
            int m = bm + mt * 16 + mr0 + r;
            if (m < M) {
                #pragma unroll
                for (int nt = 0; nt < 8; ++nt) {
                    float v = acc[mt][nt][r] + bias[nt * 16 + l16];
                    v = v > 0.f ? v : 0.f;
                    if (WB16) {
                        // h plane-sliced [4][NN][32]: plane = ch>>5, off = ch&31
                        int ch = nt * 16 + l16;
                        ((ushort*)outp)[((size_t)(ch >> 5) * NN + m) * 32 + (ch & 31)] = f2b(v);
                    } else {
                        ((float*)outp)[(size_t)m * 128 + nt * 16 + l16] = v;
                    }
                }
            }
        }
    }
}

// ---------------- launch ----------------

static inline size_t alignup(size_t x) { return (x + 255) & ~(size_t)255; }

extern "C" void kernel_launch(void* const* d_in, const int* in_sizes, int n_in,
                              void* d_out, int out_size, void* d_ws, size_t ws_size,
                              hipStream_t stream) {
    const float* x   = (const float*)d_in[0];
    const int* edge  = (const int*)d_in[1];
    const float* Wl1 = (const float*)d_in[2];
    const float* Wr1 = (const float*)d_in[3];
    const float* b1  = (const float*)d_in[4];
    const float* Wl2 = (const float*)d_in[5];
    const float* Wr2 = (const float*)d_in[6];
    const float* b2  = (const float*)d_in[7];
    float* out = (float*)d_out;

    const int* srcp = edge;
    const int* dstp = edge + NE;

    // pairbuf + partition-padded CSR live in d_out (13.6 MB of 51.2 MB);
    // both dead before gemm2 writes the real output.
    uint* pairbuf = (uint*)d_out;                       // NP*PCAP uints = 6.8 MB
    int* nbrG = (int*)d_out + (size_t)NP * PCAP;        // NP*PCAP ints  = 6.8 MB

    char* w = (char*)d_ws;
    uint* pcnt = (uint*)w;     w += alignup((size_t)NP * 4);
    uint* pack = (uint*)w;     w += alignup((size_t)NN * 4);
    ushort* xb = (ushort*)w;   w += alignup((size_t)NN * CH * 2);  // plane-sliced; reused as h
    ushort* mb = (ushort*)w;   w += alignup((size_t)NN * CH * 2);  // plane-sliced mean
    ushort* BtK1 = (ushort*)w; w += alignup((size_t)128 * 256 * 2);
    ushort* BtK2 = (ushort*)w; w += alignup((size_t)128 * 256 * 2);

    hipMemsetAsync(pcnt, 0, (size_t)NP * 4, stream);

    k_bin<<<NB, 1024, 0, stream>>>((const int4*)srcp, (const int4*)dstp, pcnt, pairbuf);
    // fused csr + x-cast + W-cast: 196 csr + 784 castx + 128 castw blocks
    k_mid<<<NP + 784 + 128, 512, 0, stream>>>(pcnt, pairbuf, nbrG, pack,
                                              x, xb, Wl1, Wr1, Wl2, Wr2, BtK1, BtK2);

    int gg = (NN + 127) / 128;
    const int YT = 1563;              // ceil(NN/64)
    const int yc[5] = {0, 391, 782, 1173, YT};
    // layer 1: agg(xb) -> mb (4 probe chunks); h = relu([mb|xb]@B1) bf16, in place over xb
    for (int c = 0; c < 4; ++c) {
        dim3 ag(4, yc[c + 1] - yc[c]);
        k_agg<<<ag, 256, 0, stream>>>((const uint4*)xb, nbrG, pack, (uint4*)mb, yc[c]);
    }
    k_gemm<true><<<gg, 256, 0, stream>>>(mb, xb, BtK1, b1, (void*)xb, NN);
    // layer 2: agg(h) -> mb (4 probe chunks); out = relu([mb|h]@B2) fp32 row-major
    for (int c = 0; c < 4; ++c) {
        dim3 ag(4, yc[c + 1] - yc[c]);
        k_agg<<<ag, 256, 0, stream>>>((const uint4*)xb, nbrG, pack, (uint4*)mb, yc[c]);
    }
    k_gemm<false><<<gg, 256, 0, stream>>>(mb, xb, BtK2, b2, (void*)out, NN);
}

// Round 11
// 357.474 us; speedup vs baseline: 1.0449x; 1.0449x over previous
//
#include <hip/hip_runtime.h>

#define NN 100000
#define NE 1600000
#define CH 128

#define PART 512               // nodes per partition
#define NP 196                 // ceil(NN/PART)
#define PCAP 8704              // pair capacity per partition (lambda~8163, +6 sd)
#define NB 391                 // bin blocks: ceil(NE/4/1024)
#define SCAP 64                // LDS slot cap per (block, partition); lambda~21
#define SLAB 1536              // agg: LDS slab cap (64 nodes, lambda~1024, +16 sd)

typedef __attribute__((ext_vector_type(8))) short bf16x8;
typedef __attribute__((ext_vector_type(4))) float f32x4;
typedef unsigned int uint;
typedef unsigned short ushort;

__device__ __forceinline__ ushort f2b(float f) {
    uint u = __builtin_bit_cast(uint, f);
    uint r = (u + 0x7fff + ((u >> 16) & 1)) >> 16;
    return (ushort)r;
}
__device__ __forceinline__ float blo(uint v) { return __builtin_bit_cast(float, v << 16); }
__device__ __forceinline__ float bhi(uint v) { return __builtin_bit_cast(float, v & 0xffff0000u); }

__device__ __forceinline__ void acc8(float* a, uint4 v) {
    a[0] += blo(v.x); a[1] += bhi(v.x);
    a[2] += blo(v.y); a[3] += bhi(v.y);
    a[4] += blo(v.z); a[5] += bhi(v.z);
    a[6] += blo(v.w); a[7] += bhi(v.w);
}

// ---------------- pass 1: LDS-binned edge partitioning ----------------
// pair = (dst_local << 17) | src ; partition p = dst >> 9. int4 edge reads.

__global__ __launch_bounds__(1024) void k_bin(const int4* __restrict__ src4, const int4* __restrict__ dst4,
                                              uint* __restrict__ pcnt, uint* __restrict__ pairbuf) {
    __shared__ uint slots[NP * SCAP];  // 50.2 KB
    __shared__ uint lcnt[NP];
    __shared__ uint lbase[NP];
    int tid = threadIdx.x;
    if (tid < NP) lcnt[tid] = 0;
    __syncthreads();
    int e4 = blockIdx.x * 1024 + tid;
    if (e4 < NE / 4) {
        int4 d4 = dst4[e4];
        int4 s4 = src4[e4];
        int dd[4] = {d4.x, d4.y, d4.z, d4.w};
        int ss[4] = {s4.x, s4.y, s4.z, s4.w};
        #pragma unroll
        for (int j = 0; j < 4; ++j) {
            int p = dd[j] >> 9;
            uint pair = ((uint)(dd[j] & 511) << 17) | (uint)ss[j];
            uint pos = atomicAdd(&lcnt[p], 1u);
            if (pos < SCAP) slots[p * SCAP + pos] = pair;
        }
    }
    __syncthreads();
    if (tid < NP) {
        uint c = lcnt[tid];
        c = c < SCAP ? c : SCAP;
        lcnt[tid] = c;
        lbase[tid] = atomicAdd(&pcnt[tid], c);
    }
    __syncthreads();
    for (int t = tid; t < NP * SCAP; t += 1024) {
        int p = t >> 6;
        uint s = (uint)(t & (SCAP - 1));
        if (s < lcnt[p]) {
            uint idx = lbase[p] + s;
            if (idx < PCAP) pairbuf[(size_t)p * PCAP + idx] = slots[t];
        }
    }
}

// ---------------- pass 2 (fused): CSR build + x cast + W cast ----------------
// blocks [0, NP): per-partition CSR build (latency-bound: <1 block/CU alone).
// blocks [NP, NP+784): x [NN][128] fp32 -> plane-sliced bf16 xb[p][n][32].
// blocks [NP+784, NP+912): k-major B for both layers.

__global__ __launch_bounds__(512) void k_mid(const uint* __restrict__ pcnt, const uint* __restrict__ pairbuf,
                                             int* __restrict__ nbrG, uint* __restrict__ pack,
                                             const float* __restrict__ x, ushort* __restrict__ xb,
                                             const float* __restrict__ Wl1, const float* __restrict__ Wr1,
                                             const float* __restrict__ Wl2, const float* __restrict__ Wr2,
                                             ushort* __restrict__ BtK1, ushort* __restrict__ BtK2) {
    __shared__ uint pairs[PCAP];   // 34.8 KB
    __shared__ uint cnt[PART];
    __shared__ uint rowptr[PART + 1];
    __shared__ uint wpart[8];
    int tid = threadIdx.x;
    int b = blockIdx.x;
    if (b >= NP) {
        int i = b - NP;
        if (i < 784) {               // x cast: plane p = i/196, 196 blocks/plane
            int p = i / 196;
            int n = (i % 196) * 512 + tid;
            if (n >= NN) return;
            const float4* sp = (const float4*)(x + (size_t)n * 128 + p * 32);
            uint4 o[4];
            ushort* op = (ushort*)o;
            #pragma unroll
            for (int q = 0; q < 8; ++q) {
                float4 v = sp[q];
                op[q * 4 + 0] = f2b(v.x);
                op[q * 4 + 1] = f2b(v.y);
                op[q * 4 + 2] = f2b(v.z);
                op[q * 4 + 3] = f2b(v.w);
            }
            uint4* dp = (uint4*)(xb + ((size_t)p * NN + n) * 32);
            #pragma unroll
            for (int q = 0; q < 4; ++q) dp[q] = o[q];
        } else {                     // W cast: BtK[kt][n][c], 128 blocks over 2*32768
            int idx = (i - 784) * 512 + tid;
            int L = idx >> 15;
            int ii = idx & 32767;
            const float* Wl = L ? Wl2 : Wl1;
            const float* Wr = L ? Wr2 : Wr1;
            ushort* BtK = L ? BtK2 : BtK1;
            int c = ii & 31;
            int n = (ii >> 5) & 127;
            int kt = ii >> 12;
            int k = kt * 32 + c;
            float v = (k < 128) ? Wl[k * 128 + n] : Wr[(k - 128) * 128 + n];
            BtK[ii] = f2b(v);
        }
        return;
    }
    // ---- CSR build for partition b ----
    int p = b;
    uint tot = pcnt[p];
    tot = tot < PCAP ? tot : PCAP;
    for (uint i = tid; i < tot; i += 512) pairs[i] = pairbuf[(size_t)p * PCAP + i];
    cnt[tid] = 0;
    __syncthreads();
    for (uint i = tid; i < tot; i += 512) atomicAdd(&cnt[pairs[i] >> 17], 1u);
    __syncthreads();
    uint deg = cnt[tid];
    uint s = deg;
    #pragma unroll
    for (int off = 1; off < 64; off <<= 1) {
        uint t = __shfl_up(s, off, 64);
        if ((tid & 63) >= off) s += t;
    }
    if ((tid & 63) == 63) wpart[tid >> 6] = s;
    __syncthreads();
    uint base = 0;
    int w = tid >> 6;
    #pragma unroll
    for (int q = 0; q < 7; ++q) base += (q < w) ? wpart[q] : 0;
    rowptr[tid] = base + s - deg;
    if (tid == 511) rowptr[512] = base + s;
    cnt[tid] = 0;  // reuse as fill counters
    __syncthreads();
    for (uint i = tid; i < tot; i += 512) {
        uint u = pairs[i];
        uint dl = u >> 17;
        uint pos = rowptr[dl] + atomicAdd(&cnt[dl], 1u);
        nbrG[(size_t)p * PCAP + pos] = (int)(u & 0x1FFFFu);
    }
    {
        int n = p * PART + tid;
        if (n < NN) {
            uint d = rowptr[tid + 1] - rowptr[tid];
            pack[n] = ((uint)(p * PCAP) + rowptr[tid]) | (d << 21);
        }
    }
}

// ---------------- mean aggregation: LDS-staged neighbor slab ----------------
// grid (4, NN/64); plane = blockIdx.x -> XCD pair {p, p+4} via linear%8.
// 4 lanes per node (32ch plane = 4 x uint4 = one 64B line/request), 64 nodes/block.

__global__ __launch_bounds__(256) void k_agg(const uint4* __restrict__ feat, const int* __restrict__ nbrG,
                                             const uint* __restrict__ pack, uint4* __restrict__ outb) {
    __shared__ int sl[SLAB];
    __shared__ int sh_s0, sh_cnt;
    int plane = blockIdx.x;
    int nb = blockIdx.y * 64;  // block node range stays within one 512-partition
    int tid = threadIdx.x;
    int n = nb + (tid >> 2);
    int h = tid & 3;
    if (tid == 0) {
        uint u0 = pack[nb];
        int last = nb + 63 < NN ? nb + 63 : NN - 1;
        uint u1 = pack[last];
        int s0 = (int)(u0 & 0x1FFFFFu);
        sh_s0 = s0;
        sh_cnt = (int)(u1 & 0x1FFFFFu) + (int)(u1 >> 21) - s0;
    }
    __syncthreads();
    int s0 = sh_s0, scnt = sh_cnt;
    bool staged = scnt <= SLAB;
    if (staged) {
        for (int i = tid; i < scnt; i += 256) sl[i] = nbrG[s0 + i];
    }
    __syncthreads();
    if (n >= NN) return;
    uint u = pack[n];
    int s = (int)(u & 0x1FFFFFu);
    int d = (int)(u >> 21);
    const char* fb = (const char*)feat + ((size_t)plane * NN) * 64;
    uint hoff = (uint)h * 16;
    float a[8] = {};
    if (staged) {
        const int* bp = sl + (s - s0);
        int i = 0;
        for (; i + 8 <= d; i += 8) {  // 8 x 64B line requests in flight
            uint off[8];
            uint4 v[8];
            #pragma unroll
            for (int j = 0; j < 8; ++j) off[j] = ((uint)bp[i + j] << 6) | hoff;
            #pragma unroll
            for (int j = 0; j < 8; ++j) v[j] = *(const uint4*)(fb + off[j]);
            #pragma unroll
            for (int j = 0; j < 8; ++j) acc8(a, v[j]);
        }
        for (; i < d; ++i) acc8(a, *(const uint4*)(fb + (((uint)bp[i] << 6) | hoff)));
    } else {  // overflow fallback (P ~ 0): global index reads
        const int* bp = nbrG + s;
        int i = 0;
        for (; i + 4 <= d; i += 4) {
            uint o0 = ((uint)bp[i] << 6) | hoff;
            uint o1 = ((uint)bp[i + 1] << 6) | hoff;
            uint o2 = ((uint)bp[i + 2] << 6) | hoff;
            uint o3 = ((uint)bp[i + 3] << 6) | hoff;
            uint4 v0 = *(const uint4*)(fb + o0);
            uint4 v1 = *(const uint4*)(fb + o1);
            uint4 v2 = *(const uint4*)(fb + o2);
            uint4 v3 = *(const uint4*)(fb + o3);
            acc8(a, v0);
            acc8(a, v1);
            acc8(a, v2);
            acc8(a, v3);
        }
        for (; i < d; ++i) acc8(a, *(const uint4*)(fb + (((uint)bp[i] << 6) | hoff)));
    }
    float id = 1.0f / fmaxf((float)d, 1.0f);
    uint4 r;
    r.x = (uint)f2b(a[0] * id) | ((uint)f2b(a[1] * id) << 16);
    r.y = (uint)f2b(a[2] * id) | ((uint)f2b(a[3] * id) << 16);
    r.z = (uint)f2b(a[4] * id) | ((uint)f2b(a[5] * id) << 16);
    r.w = (uint)f2b(a[6] * id) | ((uint)f2b(a[7] * id) << 16);
    outb[((size_t)plane * NN + n) * 4 + h] = r;
}

// ---------------- MFMA GEMM: out = relu([Am | Ax] @ B + bias) ----------------
// A plane-sliced [4][N][32] bf16; B k-major [8][128][32]. BM=128/block, 32 rows/wave.
// R11: (1) all 16 A-fragments prefetched up-front (16 wave-loads in flight, hides
// L2/L3 latency that serialized the old kt loop at MfmaUtil 4.8%); (2) LDS-staged
// epilogue -> b128 line-coalesced stores (old: 64 scalar stores/thread, 32B partial
// segments, 2x write amplification on the bf16 path per WRITE_SIZE=50MB counter).

template <bool WB16>
__global__ __launch_bounds__(256) void k_gemm(const ushort* __restrict__ Am, const ushort* Ax,
                                              const ushort* __restrict__ BtK, const float* __restrict__ bias,
                                              void* outp, int M) {
    __shared__ char smem[34816];   // ushort[4][32][136] (WB16) or float[4][16][132]
    int lane = threadIdx.x & 63;
    int wave = threadIdx.x >> 6;
    int bm = blockIdx.x * 128 + wave * 32;
    int l16 = lane & 15;
    int g = lane >> 4;
    int lk8 = g * 8;

    // prefetch all A fragments: 8 kt x 2 mt = 16 independent 1KB wave-loads
    bf16x8 af[8][2];
    #pragma unroll
    for (int kt = 0; kt < 8; ++kt) {
        const ushort* A = (kt < 4) ? Am : Ax;
        int p = kt & 3;
        #pragma unroll
        for (int mt = 0; mt < 2; ++mt) {
            int row = bm + mt * 16 + l16;
            row = row < M ? row : M - 1;
            af[kt][mt] = *(const bf16x8*)(A + ((size_t)p * NN + row) * 32 + lk8);
        }
    }
    f32x4 acc[2][8] = {};
    #pragma unroll
    for (int kt = 0; kt < 8; ++kt) {
        const ushort* Bk = BtK + (size_t)kt * 128 * 32;  // 8 KB slice, L1-hot
        #pragma unroll
        for (int nt = 0; nt < 8; ++nt) {
            bf16x8 bfr = *(const bf16x8*)(Bk + (size_t)(nt * 16 + l16) * 32 + lk8);
            acc[0][nt] = __builtin_amdgcn_mfma_f32_16x16x32_bf16(af[kt][0], bfr, acc[0][nt], 0, 0, 0);
            acc[1][nt] = __builtin_amdgcn_mfma_f32_16x16x32_bf16(af[kt][1], bfr, acc[1][nt], 0, 0, 0);
        }
    }
    // C/D layout: col = lane&15, row = g*4 + reg
    int mr0 = g * 4;
    if (WB16) {
        // stage per-wave 32x128 bf16 tile (pad 136 -> 2-way banks, free)
        ushort (*so)[136] = (ushort(*)[136])(smem + wave * 32 * 136 * 2);
        #pragma unroll
        for (int mt = 0; mt < 2; ++mt)
            #pragma unroll
            for (int r = 0; r < 4; ++r)
                #pragma unroll
                for (int nt = 0; nt < 8; ++nt) {
                    float v = acc[mt][nt][r] + bias[nt * 16 + l16];
                    so[mt * 16 + mr0 + r][nt * 16 + l16] = f2b(v > 0.f ? v : 0.f);
                }
        // readback: 512 x 16B units; 4 lanes/plane-row = 64B line-coalesced
        #pragma unroll
        for (int pass = 0; pass < 8; ++pass) {
            int u = pass * 64 + lane;
            int row = u >> 4, h16 = u & 15;
            int m = bm + row;
            if (m < M) {
                bf16x8 vv = *(const bf16x8*)&so[row][h16 * 8];
                *(bf16x8*)((ushort*)outp + ((size_t)(h16 >> 2) * NN + m) * 32 + (h16 & 3) * 8) = vv;
            }
        }
    } else {
        // stage 16 rows (one mt half) at a time: float[16][132] per wave
        float (*so)[132] = (float(*)[132])(smem + wave * 16 * 132 * 4);
        #pragma unroll
        for (int mt = 0; mt < 2; ++mt) {
            #pragma unroll
            for (int r = 0; r < 4; ++r)
                #pragma unroll
                for (int nt = 0; nt < 8; ++nt) {
                    float v = acc[mt][nt][r] + bias[nt * 16 + l16];
                    so[mr0 + r][nt * 16 + l16] = v > 0.f ? v : 0.f;
                }
            #pragma unroll
            for (int pass = 0; pass < 8; ++pass) {
                int u = pass * 64 + lane;
                int row = u >> 5, hf = u & 31;
                int m = bm + mt * 16 + row;
                if (m < M) {
                    *(f32x4*)((float*)outp + (size_t)m * 128 + hf * 4) = *(const f32x4*)&so[row][hf * 4];
                }
            }
        }
    }
}

// ---------------- launch ----------------

static inline size_t alignup(size_t x) { return (x + 255) & ~(size_t)255; }

extern "C" void kernel_launch(void* const* d_in, const int* in_sizes, int n_in,
                              void* d_out, int out_size, void* d_ws, size_t ws_size,
                              hipStream_t stream) {
    const float* x   = (const float*)d_in[0];
    const int* edge  = (const int*)d_in[1];
    const float* Wl1 = (const float*)d_in[2];
    const float* Wr1 = (const float*)d_in[3];
    const float* b1  = (const float*)d_in[4];
    const float* Wl2 = (const float*)d_in[5];
    const float* Wr2 = (const float*)d_in[6];
    const float* b2  = (const float*)d_in[7];
    float* out = (float*)d_out;

    const int* srcp = edge;
    const int* dstp = edge + NE;

    // pairbuf + partition-padded CSR live in d_out (13.6 MB of 51.2 MB);
    // both dead before gemm2 writes the real output.
    uint* pairbuf = (uint*)d_out;                       // NP*PCAP uints = 6.8 MB
    int* nbrG = (int*)d_out + (size_t)NP * PCAP;        // NP*PCAP ints  = 6.8 MB

    char* w = (char*)d_ws;
    uint* pcnt = (uint*)w;     w += alignup((size_t)NP * 4);
    uint* pack = (uint*)w;     w += alignup((size_t)NN * 4);
    ushort* xb = (ushort*)w;   w += alignup((size_t)NN * CH * 2);  // plane-sliced; reused as h
    ushort* mb = (ushort*)w;   w += alignup((size_t)NN * CH * 2);  // plane-sliced mean
    ushort* BtK1 = (ushort*)w; w += alignup((size_t)128 * 256 * 2);
    ushort* BtK2 = (ushort*)w; w += alignup((size_t)128 * 256 * 2);

    hipMemsetAsync(pcnt, 0, (size_t)NP * 4, stream);

    k_bin<<<NB, 1024, 0, stream>>>((const int4*)srcp, (const int4*)dstp, pcnt, pairbuf);
    // fused csr + x-cast + W-cast: 196 csr + 784 castx + 128 castw blocks
    k_mid<<<NP + 784 + 128, 512, 0, stream>>>(pcnt, pairbuf, nbrG, pack,
                                              x, xb, Wl1, Wr1, Wl2, Wr2, BtK1, BtK2);

    int gg = (NN + 127) / 128;
    dim3 ag(4, (NN + 63) / 64);
    // layer 1: agg(xb) -> mb; h = relu([mb|xb]@B1) bf16 plane-sliced, in place over xb
    k_agg<<<ag, 256, 0, stream>>>((const uint4*)xb, nbrG, pack, (uint4*)mb);
    k_gemm<true><<<gg, 256, 0, stream>>>(mb, xb, BtK1, b1, (void*)xb, NN);
    // layer 2: agg(h) -> mb; out = relu([mb|h]@B2) fp32 row-major (overwrites pairbuf/nbrG)
    k_agg<<<ag, 256, 0, stream>>>((const uint4*)xb, nbrG, pack, (uint4*)mb);
    k_gemm<false><<<gg, 256, 0, stream>>>(mb, xb, BtK2, b2, (void*)out, NN);
}

// Round 12
// 296.023 us; speedup vs baseline: 1.2618x; 1.2076x over previous
//
#include <hip/hip_runtime.h>

#define NN 100000
#define NE 1600000
#define CH 128

#define PART 512               // nodes per partition
#define NP 196                 // ceil(NN/PART)
#define PCAP 8704              // pair capacity per partition (lambda~8163, +6 sd)
#define NB 391                 // bin blocks: ceil(NE/4/1024)
#define SCAP 64                // LDS slot cap per (block, partition); lambda~21
#define SLAB 1536              // agg: LDS slab cap (64 nodes, lambda~1024, +16 sd)

typedef __attribute__((ext_vector_type(8))) short bf16x8;
typedef __attribute__((ext_vector_type(4))) float f32x4;
typedef unsigned int uint;
typedef unsigned short ushort;

__device__ __forceinline__ ushort f2b(float f) {
    uint u = __builtin_bit_cast(uint, f);
    uint r = (u + 0x7fff + ((u >> 16) & 1)) >> 16;
    return (ushort)r;
}
__device__ __forceinline__ float blo(uint v) { return __builtin_bit_cast(float, v << 16); }
__device__ __forceinline__ float bhi(uint v) { return __builtin_bit_cast(float, v & 0xffff0000u); }

__device__ __forceinline__ void acc8(float* a, uint4 v) {
    a[0] += blo(v.x); a[1] += bhi(v.x);
    a[2] += blo(v.y); a[3] += bhi(v.y);
    a[4] += blo(v.z); a[5] += bhi(v.z);
    a[6] += blo(v.w); a[7] += bhi(v.w);
}

// ---------------- pass 1: LDS-binned edge partitioning ----------------
// pair = (dst_local << 17) | src ; partition p = dst >> 9. int4 edge reads.

__global__ __launch_bounds__(1024) void k_bin(const int4* __restrict__ src4, const int4* __restrict__ dst4,
                                              uint* __restrict__ pcnt, uint* __restrict__ pairbuf) {
    __shared__ uint slots[NP * SCAP];  // 50.2 KB
    __shared__ uint lcnt[NP];
    __shared__ uint lbase[NP];
    int tid = threadIdx.x;
    if (tid < NP) lcnt[tid] = 0;
    __syncthreads();
    int e4 = blockIdx.x * 1024 + tid;
    if (e4 < NE / 4) {
        int4 d4 = dst4[e4];
        int4 s4 = src4[e4];
        int dd[4] = {d4.x, d4.y, d4.z, d4.w};
        int ss[4] = {s4.x, s4.y, s4.z, s4.w};
        #pragma unroll
        for (int j = 0; j < 4; ++j) {
            int p = dd[j] >> 9;
            uint pair = ((uint)(dd[j] & 511) << 17) | (uint)ss[j];
            uint pos = atomicAdd(&lcnt[p], 1u);
            if (pos < SCAP) slots[p * SCAP + pos] = pair;
        }
    }
    __syncthreads();
    if (tid < NP) {
        uint c = lcnt[tid];
        c = c < SCAP ? c : SCAP;
        lcnt[tid] = c;
        lbase[tid] = atomicAdd(&pcnt[tid], c);
    }
    __syncthreads();
    for (int t = tid; t < NP * SCAP; t += 1024) {
        int p = t >> 6;
        uint s = (uint)(t & (SCAP - 1));
        if (s < lcnt[p]) {
            uint idx = lbase[p] + s;
            if (idx < PCAP) pairbuf[(size_t)p * PCAP + idx] = slots[t];
        }
    }
}

// ---------------- pass 2 (fused): CSR build + x cast + W cast ----------------
// blocks [0, NP): per-partition CSR build (latency-bound: <1 block/CU alone).
// blocks [NP, NP+784): x [NN][128] fp32 -> plane-sliced bf16 xb[p][n][32].
// blocks [NP+784, NP+912): k-major B for both layers.

__global__ __launch_bounds__(512) void k_mid(const uint* __restrict__ pcnt, const uint* __restrict__ pairbuf,
                                             int* __restrict__ nbrG, uint* __restrict__ pack,
                                             const float* __restrict__ x, ushort* __restrict__ xb,
                                             const float* __restrict__ Wl1, const float* __restrict__ Wr1,
                                             const float* __restrict__ Wl2, const float* __restrict__ Wr2,
                                             ushort* __restrict__ BtK1, ushort* __restrict__ BtK2) {
    __shared__ uint pairs[PCAP];   // 34.8 KB
    __shared__ uint cnt[PART];
    __shared__ uint rowptr[PART + 1];
    __shared__ uint wpart[8];
    int tid = threadIdx.x;
    int b = blockIdx.x;
    if (b >= NP) {
        int i = b - NP;
        if (i < 784) {               // x cast: plane p = i/196, 196 blocks/plane
            int p = i / 196;
            int n = (i % 196) * 512 + tid;
            if (n >= NN) return;
            const float4* sp = (const float4*)(x + (size_t)n * 128 + p * 32);
            uint4 o[4];
            ushort* op = (ushort*)o;
            #pragma unroll
            for (int q = 0; q < 8; ++q) {
                float4 v = sp[q];
                op[q * 4 + 0] = f2b(v.x);
                op[q * 4 + 1] = f2b(v.y);
                op[q * 4 + 2] = f2b(v.z);
                op[q * 4 + 3] = f2b(v.w);
            }
            uint4* dp = (uint4*)(xb + ((size_t)p * NN + n) * 32);
            #pragma unroll
            for (int q = 0; q < 4; ++q) dp[q] = o[q];
        } else {                     // W cast: BtK[kt][n][c], 128 blocks over 2*32768
            int idx = (i - 784) * 512 + tid;
            int L = idx >> 15;
            int ii = idx & 32767;
            const float* Wl = L ? Wl2 : Wl1;
            const float* Wr = L ? Wr2 : Wr1;
            ushort* BtK = L ? BtK2 : BtK1;
            int c = ii & 31;
            int n = (ii >> 5) & 127;
            int kt = ii >> 12;
            int k = kt * 32 + c;
            float v = (k < 128) ? Wl[k * 128 + n] : Wr[(k - 128) * 128 + n];
            BtK[ii] = f2b(v);
        }
        return;
    }
    // ---- CSR build for partition b ----
    int p = b;
    uint tot = pcnt[p];
    tot = tot < PCAP ? tot : PCAP;
    for (uint i = tid; i < tot; i += 512) pairs[i] = pairbuf[(size_t)p * PCAP + i];
    cnt[tid] = 0;
    __syncthreads();
    for (uint i = tid; i < tot; i += 512) atomicAdd(&cnt[pairs[i] >> 17], 1u);
    __syncthreads();
    uint deg = cnt[tid];
    uint s = deg;
    #pragma unroll
    for (int off = 1; off < 64; off <<= 1) {
        uint t = __shfl_up(s, off, 64);
        if ((tid & 63) >= off) s += t;
    }
    if ((tid & 63) == 63) wpart[tid >> 6] = s;
    __syncthreads();
    uint base = 0;
    int w = tid >> 6;
    #pragma unroll
    for (int q = 0; q < 7; ++q) base += (q < w) ? wpart[q] : 0;
    rowptr[tid] = base + s - deg;
    if (tid == 511) rowptr[512] = base + s;
    cnt[tid] = 0;  // reuse as fill counters
    __syncthreads();
    for (uint i = tid; i < tot; i += 512) {
        uint u = pairs[i];
        uint dl = u >> 17;
        uint pos = rowptr[dl] + atomicAdd(&cnt[dl], 1u);
        nbrG[(size_t)p * PCAP + pos] = (int)(u & 0x1FFFFu);
    }
    {
        int n = p * PART + tid;
        if (n < NN) {
            uint d = rowptr[tid + 1] - rowptr[tid];
            pack[n] = ((uint)(p * PCAP) + rowptr[tid]) | (d << 21);
        }
    }
}

// ---------------- mean aggregation: LDS-staged neighbor slab ----------------
// grid (4, NN/64); plane = blockIdx.x -> XCD pair {p, p+4} via linear%8.
// 4 lanes per node (32ch plane = 4 x uint4 = one 64B line/request), 64 nodes/block.

__global__ __launch_bounds__(256) void k_agg(const uint4* __restrict__ feat, const int* __restrict__ nbrG,
                                             const uint* __restrict__ pack, uint4* __restrict__ outb) {
    __shared__ int sl[SLAB];
    __shared__ int sh_s0, sh_cnt;
    int plane = blockIdx.x;
    int nb = blockIdx.y * 64;  // block node range stays within one 512-partition
    int tid = threadIdx.x;
    int n = nb + (tid >> 2);
    int h = tid & 3;
    if (tid == 0) {
        uint u0 = pack[nb];
        int last = nb + 63 < NN ? nb + 63 : NN - 1;
        uint u1 = pack[last];
        int s0 = (int)(u0 & 0x1FFFFFu);
        sh_s0 = s0;
        sh_cnt = (int)(u1 & 0x1FFFFFu) + (int)(u1 >> 21) - s0;
    }
    __syncthreads();
    int s0 = sh_s0, scnt = sh_cnt;
    bool staged = scnt <= SLAB;
    if (staged) {
        for (int i = tid; i < scnt; i += 256) sl[i] = nbrG[s0 + i];
    }
    __syncthreads();
    if (n >= NN) return;
    uint u = pack[n];
    int s = (int)(u & 0x1FFFFFu);
    int d = (int)(u >> 21);
    const char* fb = (const char*)feat + ((size_t)plane * NN) * 64;
    uint hoff = (uint)h * 16;
    float a[8] = {};
    if (staged) {
        const int* bp = sl + (s - s0);
        int i = 0;
        for (; i + 8 <= d; i += 8) {  // 8 x 64B line requests in flight
            uint off[8];
            uint4 v[8];
            #pragma unroll
            for (int j = 0; j < 8; ++j) off[j] = ((uint)bp[i + j] << 6) | hoff;
            #pragma unroll
            for (int j = 0; j < 8; ++j) v[j] = *(const uint4*)(fb + off[j]);
            #pragma unroll
            for (int j = 0; j < 8; ++j) acc8(a, v[j]);
        }
        for (; i < d; ++i) acc8(a, *(const uint4*)(fb + (((uint)bp[i] << 6) | hoff)));
    } else {  // overflow fallback (P ~ 0): global index reads
        const int* bp = nbrG + s;
        int i = 0;
        for (; i + 4 <= d; i += 4) {
            uint o0 = ((uint)bp[i] << 6) | hoff;
            uint o1 = ((uint)bp[i + 1] << 6) | hoff;
            uint o2 = ((uint)bp[i + 2] << 6) | hoff;
            uint o3 = ((uint)bp[i + 3] << 6) | hoff;
            uint4 v0 = *(const uint4*)(fb + o0);
            uint4 v1 = *(const uint4*)(fb + o1);
            uint4 v2 = *(const uint4*)(fb + o2);
            uint4 v3 = *(const uint4*)(fb + o3);
            acc8(a, v0);
            acc8(a, v1);
            acc8(a, v2);
            acc8(a, v3);
        }
        for (; i < d; ++i) acc8(a, *(const uint4*)(fb + (((uint)bp[i] << 6) | hoff)));
    }
    float id = 1.0f / fmaxf((float)d, 1.0f);
    uint4 r;
    r.x = (uint)f2b(a[0] * id) | ((uint)f2b(a[1] * id) << 16);
    r.y = (uint)f2b(a[2] * id) | ((uint)f2b(a[3] * id) << 16);
    r.z = (uint)f2b(a[4] * id) | ((uint)f2b(a[5] * id) << 16);
    r.w = (uint)f2b(a[6] * id) | ((uint)f2b(a[7] * id) << 16);
    outb[((size_t)plane * NN + n) * 4 + h] = r;
}

// ---------------- MFMA GEMM v3: out = relu([Am | Ax] @ B + bias) ----------------
// BM=64/block (grid 1563 -> 6.1 blocks/CU, ALL co-resident; old grid 782 = 3/CU
// was the occupancy ceiling behind MfmaUtil 4.8%). 4 waves x 16 rows.
// B kt-slice (8 KB) double-buffered in LDS, loaded once per BLOCK (old: 64 KB
// through L1 per WAVE). ds_read XOR-swizzle (byte^=(row&7)<<4) -> conflict-free.
// 1-deep A+B prefetch (8 VGPR) overlaps next-slice loads with MFMAs.
// bf16 epilogue: per-wave LDS restage -> 64B coalesced segments (fixes the 2x
// write amplification shown by WRITE_SIZE=50MB on 25.6MB output). fp32: direct
// stores (already 64B segments, no amplification measured).

template <bool WB16>
__global__ __launch_bounds__(256) void k_gemm(const ushort* __restrict__ Am, const ushort* Ax,
                                              const ushort* __restrict__ BtK, const float* __restrict__ bias,
                                              void* outp, int M) {
    __shared__ char smem[17408];   // B dbuf 2x8KB; WB16 epilogue reuses 4x4352B
    int tid = threadIdx.x;
    int lane = tid & 63;
    int w = tid >> 6;
    int bm = blockIdx.x * 64 + w * 16;
    int l16 = lane & 15;
    int g = lane >> 4;
    int lk8 = g * 8;

    int row = bm + l16;
    row = row < M ? row : M - 1;

    // B staging: thread t covers 32 B (units uu=2t,2t+1) of the 8 KB kt-slice
    int uu0 = tid * 2;
    uint sw = ((uint)(tid >> 1) & 7) << 4;       // slice row = t>>1
    uint d0 = ((uint)uu0 * 16) ^ sw;
    uint d1 = ((uint)(uu0 + 1) * 16) ^ sw;
    uint rsw = ((uint)(l16 & 7)) << 4;           // read-side swizzle (row = nt*16+l16)

    // prologue: stage B slice 0 -> buf 0; prefetch A[0]
    {
        const uint4* gsrc = (const uint4*)BtK + uu0;
        uint4 r0 = gsrc[0], r1 = gsrc[1];
        *(uint4*)(smem + d0) = r0;
        *(uint4*)(smem + d1) = r1;
    }
    const ushort* A0 = Am;
    bf16x8 afc = *(const bf16x8*)(A0 + ((size_t)0 * NN + row) * 32 + lk8);
    __syncthreads();

    f32x4 acc[8] = {};
    #pragma unroll
    for (int kt = 0; kt < 8; ++kt) {
        int cur = kt & 1;
        uint4 r0, r1;
        bf16x8 afn;
        if (kt < 7) {
            const uint4* gsrc = (const uint4*)(BtK + (size_t)(kt + 1) * 4096) + uu0;
            r0 = gsrc[0];
            r1 = gsrc[1];
            const ushort* An = ((kt + 1) < 4) ? Am : Ax;
            int pn = (kt + 1) & 3;
            afn = *(const bf16x8*)(An + ((size_t)pn * NN + row) * 32 + lk8);
        }
        const char* bb = smem + cur * 8192;
        #pragma unroll
        for (int nt = 0; nt < 8; ++nt) {
            uint off = (((uint)(nt * 16 + l16) * 64) + (uint)g * 16) ^ rsw;
            bf16x8 bfr = *(const bf16x8*)(bb + off);
            acc[nt] = __builtin_amdgcn_mfma_f32_16x16x32_bf16(afc, bfr, acc[nt], 0, 0, 0);
        }
        if (kt < 7) {
            char* nb = smem + (cur ^ 1) * 8192;
            *(uint4*)(nb + d0) = r0;
            *(uint4*)(nb + d1) = r1;
            afc = afn;
        }
        __syncthreads();
    }

    // epilogue; C/D layout: col = lane&15, row = g*4 + reg
    int mr0 = g * 4;
    if (WB16) {
        ushort (*so)[136] = (ushort(*)[136])(smem + w * 4352);  // 16x136 ushort/wave
        #pragma unroll
        for (int r = 0; r < 4; ++r)
            #pragma unroll
            for (int nt = 0; nt < 8; ++nt) {
                float v = acc[nt][r] + bias[nt * 16 + l16];
                so[mr0 + r][nt * 16 + l16] = f2b(v > 0.f ? v : 0.f);
            }
        #pragma unroll
        for (int pass = 0; pass < 4; ++pass) {
            int u = pass * 64 + lane;          // 256 units: 16 rows x 16 x 16B
            int rr = u >> 4, h16 = u & 15;
            int m = blockIdx.x * 64 + w * 16 + rr;
            if (m < M) {
                bf16x8 vv = *(const bf16x8*)&so[rr][h16 * 8];
                *(bf16x8*)((ushort*)outp + ((size_t)(h16 >> 2) * NN + m) * 32 + (h16 & 3) * 8) = vv;
            }
        }
    } else {
        #pragma unroll
        for (int r = 0; r < 4; ++r) {
            int m = bm + mr0 + r;
            if (m < M) {
                #pragma unroll
                for (int nt = 0; nt < 8; ++nt) {
                    float v = acc[nt][r] + bias[nt * 16 + l16];
                    ((float*)outp)[(size_t)m * 128 + nt * 16 + l16] = v > 0.f ? v : 0.f;
                }
            }
        }
    }
}

// ---------------- launch ----------------

static inline size_t alignup(size_t x) { return (x + 255) & ~(size_t)255; }

extern "C" void kernel_launch(void* const* d_in, const int* in_sizes, int n_in,
                              void* d_out, int out_size, void* d_ws, size_t ws_size,
                              hipStream_t stream) {
    const float* x   = (const float*)d_in[0];
    const int* edge  = (const int*)d_in[1];
    const float* Wl1 = (const float*)d_in[2];
    const float* Wr1 = (const float*)d_in[3];
    const float* b1  = (const float*)d_in[4];
    const float* Wl2 = (const float*)d_in[5];
    const float* Wr2 = (const float*)d_in[6];
    const float* b2  = (const float*)d_in[7];
    float* out = (float*)d_out;

    const int* srcp = edge;
    const int* dstp = edge + NE;

    // pairbuf + partition-padded CSR live in d_out (13.6 MB of 51.2 MB);
    // both dead before gemm2 writes the real output.
    uint* pairbuf = (uint*)d_out;                       // NP*PCAP uints = 6.8 MB
    int* nbrG = (int*)d_out + (size_t)NP * PCAP;        // NP*PCAP ints  = 6.8 MB

    char* w = (char*)d_ws;
    uint* pcnt = (uint*)w;     w += alignup((size_t)NP * 4);
    uint* pack = (uint*)w;     w += alignup((size_t)NN * 4);
    ushort* xb = (ushort*)w;   w += alignup((size_t)NN * CH * 2);  // plane-sliced; reused as h
    ushort* mb = (ushort*)w;   w += alignup((size_t)NN * CH * 2);  // plane-sliced mean
    ushort* BtK1 = (ushort*)w; w += alignup((size_t)128 * 256 * 2);
    ushort* BtK2 = (ushort*)w; w += alignup((size_t)128 * 256 * 2);

    hipMemsetAsync(pcnt, 0, (size_t)NP * 4, stream);

    k_bin<<<NB, 1024, 0, stream>>>((const int4*)srcp, (const int4*)dstp, pcnt, pairbuf);
    // fused csr + x-cast + W-cast: 196 csr + 784 castx + 128 castw blocks
    k_mid<<<NP + 784 + 128, 512, 0, stream>>>(pcnt, pairbuf, nbrG, pack,
                                              x, xb, Wl1, Wr1, Wl2, Wr2, BtK1, BtK2);

    int gg = (NN + 63) / 64;   // BM=64 -> 1563 blocks, ~6.1/CU co-resident
    dim3 ag(4, (NN + 63) / 64);
    // layer 1: agg(xb) -> mb; h = relu([mb|xb]@B1) bf16 plane-sliced, in place over xb
    k_agg<<<ag, 256, 0, stream>>>((const uint4*)xb, nbrG, pack, (uint4*)mb);
    k_gemm<true><<<gg, 256, 0, stream>>>(mb, xb, BtK1, b1, (void*)xb, NN);
    // layer 2: agg(h) -> mb; out = relu([mb|h]@B2) fp32 row-major (overwrites pairbuf/nbrG)
    k_agg<<<ag, 256, 0, stream>>>((const uint4*)xb, nbrG, pack, (uint4*)mb);
    k_gemm<false><<<gg, 256, 0, stream>>>(mb, xb, BtK2, b2, (void*)out, NN);
}